// Round 3
// baseline (2077.099 us; speedup 1.0000x reference)
//
#include <hip/hip_runtime.h>
#include <hip/hip_fp16.h>

#define IMG_H 512
#define IMG_W 512
#define WOUT  112          // output cols per block
#define WV    128          // WOUT + 16 halo cols (power of 2 -> shift/mask addressing)
#define NRING 24           // circular input row slots (16 halo + 8 step rows)
#define RS    8            // rows per step
#define NSTEP 8            // steps per block (64-row strip)
#define C1F   1.0e-4f
#define C2F   9.0e-4f

// ---------------------------------------------------------------------------
// prep: extract exact separable 1D weights from the 2D filters.
// g2d[i][j] == v[i]*v[j] with v[j] = g[h][j]/sqrt(g[h][h])  (outer product).
// ws layout (floats): [0..4]=w5, [8..18]=w11, [32..48]=w17
// ---------------------------------------------------------------------------
__global__ void prep_weights_kernel(const float* __restrict__ g0,
                                    const float* __restrict__ g1,
                                    const float* __restrict__ g2,
                                    float* __restrict__ ws) {
  if (blockIdx.x == 0 && threadIdx.x == 0) {
    const float* gs[3] = {g0, g1, g2};
    const int ks[3]  = {5, 11, 17};
    const int off[3] = {0, 8, 32};
    for (int s = 0; s < 3; ++s) {
      const float* g = gs[s];
      int k = ks[s], h = k / 2;
      double rs = 1.0 / sqrt((double)g[h * k + h]);
      for (int j = 0; j < k; ++j)
        ws[off[s] + j] = (float)((double)g[h * k + j] * rs);
    }
  }
}

__device__ __forceinline__ float to_sgpr(float x) {
  int i = __builtin_amdgcn_readfirstlane(__builtin_bit_cast(int, x));
  return __builtin_bit_cast(float, i);
}

__device__ __forceinline__ int mod24(int x) {  // valid for 0 <= x < ~1500
  return x - 24 * ((x * 2731) >> 16);
}

struct __attribute__((aligned(8))) H4 { __half2 a, b; };

__device__ __forceinline__ void store_h4(__half* p, const float (&v)[4]) {
  H4 h;
  h.a = __halves2half2(__float2half(v[0]), __float2half(v[1]));  // RNE
  h.b = __halves2half2(__float2half(v[2]), __float2half(v[3]));
  *(H4*)p = h;                                                    // ds_write_b64
}

// ---------------------------------------------------------------------------
// staging: one float4 (4 cols) per thread for an 8-row group. 256 tasks exact.
// split into load (early issue, regs) + store (after V reads drain).
// sin_ layout: [slot][2][WV] floats; slot(row r) = (r + 8) mod 24
// ---------------------------------------------------------------------------
struct StageRegs { float4 v1, v2; int slot, cb; };

__device__ __forceinline__ StageRegs stage_load(const float* __restrict__ p1,
                                                const float* __restrict__ p2,
                                                int gr0, int x0, int tid) {
  StageRegs s;
  int rr  = tid >> 5;
  int cc4 = tid & 31;
  int gr  = gr0 + rr;
  int gc  = x0 - 8 + 4 * cc4;
  s.v1 = make_float4(0.f, 0.f, 0.f, 0.f);
  s.v2 = make_float4(0.f, 0.f, 0.f, 0.f);
  if ((unsigned)gr < (unsigned)IMG_H) {
    const float* r1 = p1 + gr * IMG_W;
    const float* r2 = p2 + gr * IMG_W;
    if ((unsigned)gc <= (unsigned)(IMG_W - 4)) {
      s.v1 = *(const float4*)(r1 + gc);
      s.v2 = *(const float4*)(r2 + gc);
    } else {
      float* a = (float*)&s.v1;
      float* b = (float*)&s.v2;
      #pragma unroll
      for (int k = 0; k < 4; ++k) {
        int c = gc + k;
        if ((unsigned)c < (unsigned)IMG_W) { a[k] = r1[c]; b[k] = r2[c]; }
      }
    }
  }
  s.slot = mod24(gr + 56);          // == (gr+8) mod 24, gr >= -8
  s.cb   = 4 * cc4;
  return s;
}

__device__ __forceinline__ void stage_store(const StageRegs& s,
                                            float* __restrict__ sin_) {
  float* p = sin_ + s.slot * (2 * WV) + s.cb;
  *(float4*)(p)      = s.v1;        // ds_write_b128
  *(float4*)(p + WV) = s.v2;
}

// ---------------------------------------------------------------------------
// vertical pass: thread tid -> (rr = tid>>5, 4-col group cc = tid&31).
// products recomputed from b1/b2 (2 b128 reads per tap row); fp16 stores.
// svh layout: [5 planes][RS rows][WV cols] halves
// ---------------------------------------------------------------------------
template<int K>
__device__ __forceinline__ void v_col(const float (&wk)[K],
                                      const float* __restrict__ sin_,
                                      __half* __restrict__ svh,
                                      int yc, int tid) {
  constexpr int HK = K / 2;
  const int rr = tid >> 5;
  const int cc = tid & 31;
  float a0[4] = {0,0,0,0}, a1[4] = {0,0,0,0}, a2[4] = {0,0,0,0},
        a3[4] = {0,0,0,0}, a4[4] = {0,0,0,0};
  int slot = mod24(yc + rr - HK + 56);
  const int cb = 4 * cc;
  #pragma unroll
  for (int tap = 0; tap < K; ++tap) {
    const float* row = sin_ + slot * (2 * WV) + cb;
    float4 A = *(const float4*)(row);        // b1, 4 cols
    float4 B = *(const float4*)(row + WV);   // b2, 4 cols
    float w = wk[tap];
    a0[0] = fmaf(w, A.x,        a0[0]);
    a1[0] = fmaf(w, B.x,        a1[0]);
    a2[0] = fmaf(w, A.x * A.x,  a2[0]);
    a3[0] = fmaf(w, B.x * B.x,  a3[0]);
    a4[0] = fmaf(w, A.x * B.x,  a4[0]);
    a0[1] = fmaf(w, A.y,        a0[1]);
    a1[1] = fmaf(w, B.y,        a1[1]);
    a2[1] = fmaf(w, A.y * A.y,  a2[1]);
    a3[1] = fmaf(w, B.y * B.y,  a3[1]);
    a4[1] = fmaf(w, A.y * B.y,  a4[1]);
    a0[2] = fmaf(w, A.z,        a0[2]);
    a1[2] = fmaf(w, B.z,        a1[2]);
    a2[2] = fmaf(w, A.z * A.z,  a2[2]);
    a3[2] = fmaf(w, B.z * B.z,  a3[2]);
    a4[2] = fmaf(w, A.z * B.z,  a4[2]);
    a0[3] = fmaf(w, A.w,        a0[3]);
    a1[3] = fmaf(w, B.w,        a1[3]);
    a2[3] = fmaf(w, A.w * A.w,  a2[3]);
    a3[3] = fmaf(w, B.w * B.w,  a3[3]);
    a4[3] = fmaf(w, A.w * B.w,  a4[3]);
    slot++;
    if (slot == NRING) slot = 0;
  }
  __half* vb = svh + rr * WV + cb;
  constexpr int PS = RS * WV;              // plane stride (halves)
  store_h4(vb + 0 * PS, a0);
  store_h4(vb + 1 * PS, a1);
  store_h4(vb + 2 * PS, a2);
  store_h4(vb + 3 * PS, a3);
  store_h4(vb + 4 * PS, a4);
}

// ---------------------------------------------------------------------------
// horizontal pass + partial ssim for (row rr, 4-col group g). fp16 reads.
// sv col index: output col c <-> c+8.  window for out col 4g+jj, half-width h:
//   K=17: idx [4g,     4g+19] -> 5 uint2 chunks @ 4g,   OFF=0
//   K=11: idx [4g+3,   4g+16] -> 5 uint2 chunks @ 4g,   OFF=3
//   K=5 : idx [4g+6,   4g+13] -> 3 uint2 chunks @ 4g+4, OFF=2
// ---------------------------------------------------------------------------
template<int K>
__device__ __forceinline__ void h_col(const float (&wk)[K],
                                      const __half* __restrict__ svh,
                                      int rr, int g, float (&accs)[4]) {
  constexpr int CHB = (K == 5) ? 4 : 0;
  constexpr int NCH = (K == 5) ? 3 : 5;
  constexpr int OFF = (K == 17) ? 0 : (K == 11 ? 3 : 2);
  float conv[5][4];
  #pragma unroll
  for (int d = 0; d < 5; ++d) {
    const __half* vb = svh + (d * RS + rr) * WV + 4 * g + CHB;
    __half wh[NCH * 4] __attribute__((aligned(8)));
    #pragma unroll
    for (int q = 0; q < NCH; ++q)
      *(uint2*)&wh[4 * q] = *(const uint2*)(vb + 4 * q);   // ds_read_b64
    #pragma unroll
    for (int j = 0; j < 4; ++j) {
      float s = 0.f;
      #pragma unroll
      for (int t = 0; t < K; ++t)
        s = fmaf(wk[t], __half2float(wh[j + OFF + t]), s); // v_fma_mix candidates
      conv[d][j] = s;
    }
  }
  #pragma unroll
  for (int j = 0; j < 4; ++j) {
    float mu1 = conv[0][j], mu2 = conv[1][j];
    float s11 = conv[2][j], s22 = conv[3][j], s12 = conv[4][j];
    float mu11 = mu1 * mu1, mu22 = mu2 * mu2, mu12 = mu1 * mu2;
    float sg1  = fabsf(s11 - mu11);
    float sg2  = fabsf(s22 - mu22);
    float sg12 = s12 - mu12;
    float num  = fmaf(2.f, mu12, C1F) * fmaf(2.f, sg12, C2F);
    float den  = (mu11 + mu22 + C1F) * (sg1 + sg2 + C2F);
    float ssim = __fdividef(num, den);
    accs[j] += fminf(1.f, fmaxf(-1.f, ssim));
  }
}

// ---------------------------------------------------------------------------
// main fused kernel: grid = 96 images * 8 row-strips * 5 col-blocks = 3840
// block = 256 threads; LDS = 24576 (fp32 input ring) + 10272 (fp16 V planes)
//   = 34.8 KB -> 4 blocks/CU (16 waves/CU); 6 barriers per 8-row step.
// Staging global loads issue at step top; LDS store lands after the V5
// barrier, overlapping H5 (HBM latency fully hidden inside the step).
// ---------------------------------------------------------------------------
__global__ __launch_bounds__(256, 4)
void mssim_kernel(const float* __restrict__ b1, const float* __restrict__ b2,
                  const float* __restrict__ ws, float* __restrict__ out) {
  __shared__ __attribute__((aligned(16))) float  sin_[NRING * WV * 2];
  __shared__ __attribute__((aligned(16))) __half svh[5 * RS * WV + 16];  // +pad: g>=28 overread

  const int tid = threadIdx.x;
  const int bid = blockIdx.x;
  const int img   = bid / 40;
  const int rem   = bid - img * 40;
  const int strip = rem / 5;            // 0..7
  const int cbk   = rem - strip * 5;    // 0..4
  const int y0 = strip * (RS * NSTEP);
  const int x0 = cbk * WOUT;            // 0,112,224,336,448
  const float* p1 = b1 + img * (IMG_H * IMG_W);
  const float* p2 = b2 + img * (IMG_H * IMG_W);
  float*       po = out + img * (IMG_H * IMG_W);

  // weights -> SGPRs
  float w17[17], w11[11], w5[5];
  #pragma unroll
  for (int i = 0; i < 17; ++i) w17[i] = to_sgpr(ws[32 + i]);
  #pragma unroll
  for (int i = 0; i < 11; ++i) w11[i] = to_sgpr(ws[8 + i]);
  #pragma unroll
  for (int i = 0; i < 5;  ++i) w5[i]  = to_sgpr(ws[i]);

  // preload rows y0-8 .. y0+15
  { StageRegs s = stage_load(p1, p2, y0 - 8, x0, tid); stage_store(s, sin_); }
  { StageRegs s = stage_load(p1, p2, y0,     x0, tid); stage_store(s, sin_); }
  { StageRegs s = stage_load(p1, p2, y0 + 8, x0, tid); stage_store(s, sin_); }

  const int hr = tid >> 5;              // H row within step (0..7)
  const int hg = tid & 31;              // H 4-col group (0..31; >=28 compute-only)
  const bool wr_ok = (hg < 28) && (x0 + 4 * hg < IMG_W);
  float* pout = po + x0 + 4 * hg;

  #pragma unroll 1
  for (int step = 0; step < NSTEP; ++step) {
    const int yc = y0 + step * RS;
    __syncthreads();   // staged rows visible; prev-step H5 done with svh

    // issue next step's global loads now (consumed after the V5 barrier)
    StageRegs snext = stage_load(p1, p2, yc + 16, x0, tid);

    float accs[4] = {0.f, 0.f, 0.f, 0.f};

    v_col<17>(w17, sin_, svh, yc, tid);
    __syncthreads();
    h_col<17>(w17, svh, hr, hg, accs);
    __syncthreads();

    v_col<11>(w11, sin_, svh, yc, tid);
    __syncthreads();
    h_col<11>(w11, svh, hr, hg, accs);
    __syncthreads();

    v_col<5>(w5, sin_, svh, yc, tid);
    __syncthreads();   // all sin_ reads for this step complete after this point
    stage_store(snext, sin_);            // overlaps H5
    h_col<5>(w5, svh, hr, hg, accs);

    // out = 0.25 + sum(clip_s)/12
    if (wr_ok) {
      float4 o = make_float4(0.25f + accs[0] * (1.f / 12.f),
                             0.25f + accs[1] * (1.f / 12.f),
                             0.25f + accs[2] * (1.f / 12.f),
                             0.25f + accs[3] * (1.f / 12.f));
      *(float4*)(pout + (yc + hr) * IMG_W) = o;
    }
  }
}

extern "C" void kernel_launch(void* const* d_in, const int* in_sizes, int n_in,
                              void* d_out, int out_size, void* d_ws, size_t ws_size,
                              hipStream_t stream) {
  const float* b1 = (const float*)d_in[0];
  const float* b2 = (const float*)d_in[1];
  const float* g0 = (const float*)d_in[2];
  const float* g1 = (const float*)d_in[3];
  const float* g2 = (const float*)d_in[4];
  float* ws  = (float*)d_ws;
  float* out = (float*)d_out;

  prep_weights_kernel<<<1, 64, 0, stream>>>(g0, g1, g2, ws);
  mssim_kernel<<<3840, 256, 0, stream>>>(b1, b2, ws, out);
}